// Round 3
// baseline (2207.316 us; speedup 1.0000x reference)
//
#include <hip/hip_runtime.h>
#include <hip/hip_bf16.h>
#include <cstdint>
#include <cstddef>

// Model constants
#define VOCAB 32000
#define DMODEL 512
#define NLAYERS 6
#define DINNER 1024
#define DSTATE 16
#define DCONV 4
#define DTRANK 32
#define BB 2
#define LL 1024
#define ROWS (BB * LL)   // 2048

typedef _Float16 half8 __attribute__((ext_vector_type(8)));
typedef float floatx4 __attribute__((ext_vector_type(4)));

// ---------------------------------------------------------------------------
// Embedding gather
__global__ __launch_bounds__(128) void embed_k(const int* __restrict__ tokens,
                                               const float* __restrict__ embed,
                                               float* __restrict__ x) {
    int row = blockIdx.x;
    int tid = threadIdx.x;
    int tok = tokens[row];
    *(float4*)(x + (size_t)row * DMODEL + tid * 4) =
        *(const float4*)(embed + (size_t)tok * DMODEL + tid * 4);
}

// ---------------------------------------------------------------------------
// Split-f16 MFMA GEMM: C[M,N] = A[M,K] @ W[N,K]^T, fp32 in/out.
// v = hi + lo (f16); C = Ah*Bh + Ah*Bl + Al*Bh  (rel err ~2^-21).
// BK=32, 256 threads = 4 waves (2x2), wave tile (BM/2)x(BN/2).
// LDS: [row][64] halves, 16B chunks XOR-swizzled by (row&7).
// MODE 0: generic bijective XCD swizzle (grid % 8 == 0).
// MODE 1: head col-slice mapping — grid = 256*16 padded, each XCD owns a
//         32-wide bx slice (W L2-resident), by inner; early-exit bx >= NBX.
template<int BM, int BN, int MODE>
__global__ __launch_bounds__(256) void gemm_split(
    const float* __restrict__ A, int lda,
    const float* __restrict__ W, int ldw,
    float* __restrict__ C, int ldc,
    int K, int NBX)
{
    constexpr int FM = BM / 32;
    constexpr int FN = BN / 32;
    __shared__ __attribute__((aligned(16))) _Float16 As[BM * 64];
    __shared__ __attribute__((aligned(16))) _Float16 Bs[BN * 64];

    int bid = blockIdx.x;
    int bx, by;
    if (MODE == 1) {
        int xcd = bid & 7, j = bid >> 3;      // j in [0,512)
        bx = xcd * 32 + (j >> 4);             // [0,256)
        by = j & 15;
        if (bx >= NBX) return;
    } else {
        int cpx = gridDim.x >> 3;
        int swz = (bid & 7) * cpx + (bid >> 3);
        bx = swz % NBX;
        by = swz / NBX;
    }
    int m0 = by * BM, n0 = bx * BN;

    int tid = threadIdx.x;
    int wid = tid >> 6, lane = tid & 63;
    int wm = wid >> 1, wn = wid & 1;
    int lr = lane & 15, lk = lane >> 4;

    floatx4 acc[FM][FN] = {};

    constexpr int ACH = BM * 4;
    constexpr int TOT = (BM + BN) * 4;

    for (int k0 = 0; k0 < K; k0 += 32) {
#pragma unroll
        for (int i = tid; i < TOT; i += 256) {
            bool isA = i < ACH;
            int j = isA ? i : i - ACH;
            int r = j >> 2, c8 = j & 3;
            const float* src = isA ? (A + (size_t)(m0 + r) * lda + k0 + c8 * 8)
                                   : (W + (size_t)(n0 + r) * ldw + k0 + c8 * 8);
            float4 v0 = *(const float4*)(src);
            float4 v1 = *(const float4*)(src + 4);
            float vv[8] = {v0.x, v0.y, v0.z, v0.w, v1.x, v1.y, v1.z, v1.w};
            half8 hi, lo;
#pragma unroll
            for (int e = 0; e < 8; ++e) {
                _Float16 h = (_Float16)vv[e];
                hi[e] = h;
                lo[e] = (_Float16)(vv[e] - (float)h);
            }
            _Float16* dst = (isA ? As : Bs) + r * 64;
            *(half8*)(dst + (((c8)     ^ (r & 7)) << 3)) = hi;
            *(half8*)(dst + (((c8 + 4) ^ (r & 7)) << 3)) = lo;
        }
        __syncthreads();

        half8 ah[FM], al[FM], bh[FN], bl[FN];
#pragma unroll
        for (int f = 0; f < FM; ++f) {
            int r = wm * (BM / 2) + f * 16 + lr;
            const _Float16* p = As + r * 64;
            ah[f] = *(const half8*)(p + (((lk)     ^ (r & 7)) << 3));
            al[f] = *(const half8*)(p + (((lk + 4) ^ (r & 7)) << 3));
        }
#pragma unroll
        for (int f = 0; f < FN; ++f) {
            int r = wn * (BN / 2) + f * 16 + lr;
            const _Float16* p = Bs + r * 64;
            bh[f] = *(const half8*)(p + (((lk)     ^ (r & 7)) << 3));
            bl[f] = *(const half8*)(p + (((lk + 4) ^ (r & 7)) << 3));
        }
#pragma unroll
        for (int i2 = 0; i2 < FM; ++i2)
#pragma unroll
            for (int j2 = 0; j2 < FN; ++j2) {
                acc[i2][j2] = __builtin_amdgcn_mfma_f32_16x16x32_f16(ah[i2], bh[j2], acc[i2][j2], 0, 0, 0);
                acc[i2][j2] = __builtin_amdgcn_mfma_f32_16x16x32_f16(ah[i2], bl[j2], acc[i2][j2], 0, 0, 0);
                acc[i2][j2] = __builtin_amdgcn_mfma_f32_16x16x32_f16(al[i2], bh[j2], acc[i2][j2], 0, 0, 0);
            }
        __syncthreads();
    }

    // epilogue: C/D map col=lane&15, row=(lane>>4)*4+reg (m89)
#pragma unroll
    for (int f = 0; f < FM; ++f)
#pragma unroll
        for (int g = 0; g < FN; ++g) {
            int row = m0 + wm * (BM / 2) + f * 16 + (lane >> 4) * 4;
            int col = n0 + wn * (BN / 2) + g * 16 + (lane & 15);
#pragma unroll
            for (int j = 0; j < 4; ++j)
                C[(size_t)(row + j) * ldc + col] = acc[f][g][j];
        }
}

// ---------------------------------------------------------------------------
// Causal depthwise conv (width 4) + bias + SiLU.
__global__ __launch_bounds__(256) void conv_silu(const float* __restrict__ xz,
                                                 const float* __restrict__ cw,
                                                 const float* __restrict__ cb,
                                                 float* __restrict__ xi) {
    int idx = blockIdx.x * 256 + threadIdx.x;
    int d = idx & 1023;
    int t = (idx >> 10) & 1023;
    int b = idx >> 20;
    const float* base = xz + (size_t)(b * LL) * (2 * DINNER) + d;
    float acc = cb[d];
#pragma unroll
    for (int j = 0; j < DCONV; ++j) {
        int tt = t - 3 + j;
        if (tt >= 0) acc += cw[d * 4 + j] * base[(size_t)tt * (2 * DINNER)];
    }
    float s = acc / (1.f + expf(-acc));
    xi[idx] = s;
}

// ---------------------------------------------------------------------------
// Selective scan, chunked: 8 chunks x 128 steps, with dt_proj+softplus FUSED.
// Block = 16 channels x 16 states (256 thr). delta computed from dbc[:,0:32]
// against the block's dtw slice during staging.
template <int PASS>
__global__ __launch_bounds__(256) void scan_k(
    const float* __restrict__ xi, const float* __restrict__ dbc,
    const float* __restrict__ dtw, const float* __restrict__ dtb,
    const float* __restrict__ A_log, const float* __restrict__ Dskip,
    const float* __restrict__ xz,
    float* __restrict__ P, float* __restrict__ S,
    const float* __restrict__ H0, float* __restrict__ yg)
{
    __shared__ float sd[128][16], sx[128][16], sB[128][16], sC[128][16], sY[128][16];
    __shared__ float sdt[16][33];   // dtw slice, padded (bank-conflict-free)
    __shared__ float sdb[128][32];  // dbc[:,0:32] rows for this chunk
    __shared__ float sdtb[16];
    int c = blockIdx.x, dblk = blockIdx.y, b = blockIdx.z;
    int tid = threadIdx.x;
    int d0 = dblk * 16;
    int t0 = c * 128;

    for (int idx = tid; idx < 512; idx += 256)
        sdt[idx >> 5][idx & 31] = dtw[(size_t)(d0 + (idx >> 5)) * DTRANK + (idx & 31)];
    if (tid < 16) sdtb[tid] = dtb[d0 + tid];

    for (int idx = tid; idx < 128 * 16; idx += 256) {
        int t = idx >> 4, i = idx & 15;
        size_t row = (size_t)(b * LL + t0 + t);
        sx[t][i] = xi[row * DINNER + d0 + i];
        sB[t][i] = dbc[row * 64 + DTRANK + i];
        if (PASS == 3) sC[t][i] = dbc[row * 64 + DTRANK + DSTATE + i];
    }
    for (int idx = tid; idx < 128 * 8; idx += 256) {
        int t = idx >> 3, q = idx & 7;
        size_t row = (size_t)(b * LL + t0 + t);
        *(float4*)&sdb[t][q * 4] = *(const float4*)(dbc + row * 64 + q * 4);
    }
    __syncthreads();

    // delta = softplus(dbc[:,0:32] @ dtw[d]^T + dtb[d])
    for (int idx = tid; idx < 128 * 16; idx += 256) {
        int t = idx >> 4, i = idx & 15;
        float a = sdtb[i];
#pragma unroll
        for (int k = 0; k < DTRANK; ++k) a += sdb[t][k] * sdt[i][k];
        sd[t][i] = (a > 20.f) ? a : log1pf(expf(a));
    }
    __syncthreads();

    int di = tid >> 4, n = tid & 15;
    int d = d0 + di;
    float Adn = -expf(A_log[d * DSTATE + n]);
    float Dsk = Dskip[d];
    float h, ap = 1.f;
    if (PASS == 1) h = 0.f;
    else           h = H0[(size_t)(c * 2 + b) * 16384 + d * 16 + n];

    for (int t = 0; t < 128; ++t) {
        float dl = sd[t][di];
        float dA = expf(dl * Adn);
        h = dA * h + dl * sx[t][di] * sB[t][n];
        if (PASS == 1) {
            ap *= dA;
        } else {
            float p = h * sC[t][n];
            p += __shfl_xor(p, 1);
            p += __shfl_xor(p, 2);
            p += __shfl_xor(p, 4);
            p += __shfl_xor(p, 8);
            if (n == 0) sY[t][di] = p + sx[t][di] * Dsk;
        }
    }

    if (PASS == 1) {
        size_t o = (size_t)(c * 2 + b) * 16384 + d * 16 + n;
        P[o] = ap;
        S[o] = h;
    } else {
        __syncthreads();
        for (int idx = tid; idx < 128 * 16; idx += 256) {
            int t = idx >> 4, i = idx & 15;
            size_t row = (size_t)(b * LL + t0 + t);
            float z = xz[row * (2 * DINNER) + DINNER + d0 + i];
            float y = sY[t][i];
            yg[row * DINNER + d0 + i] = y * (z / (1.f + expf(-z)));
        }
    }
}

// Chunk-carry prefix.
__global__ __launch_bounds__(256) void scan_carry(const float* __restrict__ P,
                                                  const float* __restrict__ S,
                                                  float* __restrict__ H0) {
    int idx = blockIdx.x * 256 + threadIdx.x;
    float carry = 0.f;
#pragma unroll
    for (int c = 0; c < 8; ++c) {
        H0[(size_t)c * 32768 + idx] = carry;
        carry = P[(size_t)c * 32768 + idx] * carry + S[(size_t)c * 32768 + idx];
    }
}

// ---------------------------------------------------------------------------
// LayerNorm over last dim 512.
__global__ __launch_bounds__(128) void lnorm(const float* __restrict__ x,
                                             const float* __restrict__ w,
                                             const float* __restrict__ bp,
                                             float* __restrict__ xn) {
    int row = blockIdx.x;
    int tid = threadIdx.x;
    float4 v = *(const float4*)(x + (size_t)row * DMODEL + tid * 4);
    float s = v.x + v.y + v.z + v.w;
    float q = v.x * v.x + v.y * v.y + v.z * v.z + v.w * v.w;
#pragma unroll
    for (int m = 1; m < 64; m <<= 1) {
        s += __shfl_xor(s, m);
        q += __shfl_xor(q, m);
    }
    __shared__ float ss[2], qq[2];
    if ((tid & 63) == 0) { ss[tid >> 6] = s; qq[tid >> 6] = q; }
    __syncthreads();
    s = ss[0] + ss[1];
    q = qq[0] + qq[1];
    float mu = s / (float)DMODEL;
    float var = q / (float)DMODEL - mu * mu;
    float r = rsqrtf(var + 1e-5f);
    int c = tid * 4;
    float4 o;
    o.x = (v.x - mu) * r * w[c + 0] + bp[c + 0];
    o.y = (v.y - mu) * r * w[c + 1] + bp[c + 1];
    o.z = (v.z - mu) * r * w[c + 2] + bp[c + 2];
    o.w = (v.w - mu) * r * w[c + 3] + bp[c + 3];
    *(float4*)(xn + (size_t)row * DMODEL + c) = o;
}

// ---------------------------------------------------------------------------
extern "C" void kernel_launch(void* const* d_in, const int* in_sizes, int n_in,
                              void* d_out, int out_size, void* d_ws, size_t ws_size,
                              hipStream_t stream) {
    const int*   tokens = (const int*)d_in[0];
    const float* embed  = (const float*)d_in[1];
    const float* inw    = (const float*)d_in[2];
    const float* cw     = (const float*)d_in[3];
    const float* cb     = (const float*)d_in[4];
    const float* xpw    = (const float*)d_in[5];
    const float* dtw    = (const float*)d_in[6];
    const float* dtb    = (const float*)d_in[7];
    const float* Alog   = (const float*)d_in[8];
    const float* Dsk    = (const float*)d_in[9];
    const float* outw   = (const float*)d_in[10];
    const float* nw     = (const float*)d_in[11];
    const float* nb     = (const float*)d_in[12];
    const float* hw     = (const float*)d_in[13];
    float* out = (float*)d_out;

    float* ws = (float*)d_ws;
    float* x   = ws;                    // ROWS*DMODEL
    float* xz  = x   + (1 << 20);       // ROWS*2*DINNER
    float* xib = xz  + (4 << 20);       // ROWS*DINNER
    float* dbc = xib + (2 << 20);       // ROWS*64
    float* yg  = dbc + (1 << 17);       // ROWS*DINNER
    float* xn  = yg  + (2 << 20);       // ROWS*DMODEL
    float* Pb  = xn  + (1 << 20);       // 8*2*1024*16
    float* Sb  = Pb  + (1 << 18);
    float* H0  = Sb  + (1 << 18);

    embed_k<<<ROWS, 128, 0, stream>>>(tokens, embed, x);

    for (int l = 0; l < NLAYERS; ++l) {
        const float* inw_l  = inw  + (size_t)l * 2 * DINNER * DMODEL;
        const float* cw_l   = cw   + (size_t)l * DINNER * DCONV;
        const float* cb_l   = cb   + (size_t)l * DINNER;
        const float* xpw_l  = xpw  + (size_t)l * 64 * DINNER;
        const float* dtw_l  = dtw  + (size_t)l * DINNER * DTRANK;
        const float* dtb_l  = dtb  + (size_t)l * DINNER;
        const float* Alog_l = Alog + (size_t)l * DINNER * DSTATE;
        const float* Dsk_l  = Dsk  + (size_t)l * DINNER;
        const float* outw_l = outw + (size_t)l * DMODEL * DINNER;

        // xz = x @ inw^T   [2048, 2048], K=512
        gemm_split<128, 128, 0><<<16 * 16, 256, 0, stream>>>(
            x, DMODEL, inw_l, DMODEL, xz, 2 * DINNER, DMODEL, 16);
        // xi = silu(causal_conv(xz[:, :DINNER]) + cb)
        conv_silu<<<(ROWS * DINNER) / 256, 256, 0, stream>>>(xz, cw_l, cb_l, xib);
        // dbc = xi @ xpw^T   [2048, 64], K=1024 (MFMA split-f16)
        gemm_split<128, 64, 0><<<16, 256, 0, stream>>>(
            xib, DINNER, xpw_l, DINNER, dbc, 64, DINNER, 1);
        // selective scan (dt_proj fused), 3 passes
        scan_k<1><<<dim3(8, DINNER / 16, BB), 256, 0, stream>>>(
            xib, dbc, dtw_l, dtb_l, Alog_l, Dsk_l, xz, Pb, Sb, nullptr, nullptr);
        scan_carry<<<128, 256, 0, stream>>>(Pb, Sb, H0);
        scan_k<3><<<dim3(8, DINNER / 16, BB), 256, 0, stream>>>(
            xib, dbc, dtw_l, dtb_l, Alog_l, Dsk_l, xz, nullptr, nullptr, H0, yg);
        // x = yg @ outw^T   [2048, 512], K=1024
        gemm_split<64, 64, 0><<<32 * 8, 256, 0, stream>>>(
            yg, DINNER, outw_l, DINNER, x, DMODEL, DINNER, 8);
    }

    lnorm<<<ROWS, 128, 0, stream>>>(x, nw, nb, xn);
    // logits = xn @ head_w^T  [2048, 32000] — col-slice-per-XCD mapping
    gemm_split<128, 128, 1><<<256 * 16, 256, 0, stream>>>(
        xn, DMODEL, hw, DMODEL, out, VOCAB, DMODEL, 250);
}

// Round 4
// 1758.376 us; speedup vs baseline: 1.2553x; 1.2553x over previous
//
#include <hip/hip_runtime.h>
#include <hip/hip_bf16.h>
#include <cstdint>
#include <cstddef>

// Model constants
#define VOCAB 32000
#define DMODEL 512
#define NLAYERS 6
#define DINNER 1024
#define DSTATE 16
#define DCONV 4
#define DTRANK 32
#define BB 2
#define LL 1024
#define ROWS (BB * LL)   // 2048
#define CHUNK 64
#define NCH 16

typedef _Float16 half8 __attribute__((ext_vector_type(8)));
typedef float floatx4 __attribute__((ext_vector_type(4)));

__device__ __forceinline__ void gload16(const _Float16* g, _Float16* l) {
    __builtin_amdgcn_global_load_lds(
        (const __attribute__((address_space(1))) unsigned int*)g,
        (__attribute__((address_space(3))) unsigned int*)l, 16, 0, 0);
}

// ---------------------------------------------------------------------------
__global__ __launch_bounds__(128) void embed_k(const int* __restrict__ tokens,
                                               const float* __restrict__ embed,
                                               float* __restrict__ x) {
    int row = blockIdx.x;
    int tid = threadIdx.x;
    int tok = tokens[row];
    *(float4*)(x + (size_t)row * DMODEL + tid * 4) =
        *(const float4*)(embed + (size_t)tok * DMODEL + tid * 4);
}

// ---------------------------------------------------------------------------
// Split-f16 MFMA GEMM, double-buffered LDS + register prefetch (T14).
// C[M,N] = A[M,K] @ W[N,K]^T fp32 in/out; v = hi+lo f16; 3-MFMA split.
// One __syncthreads per K-step; next-step global loads issued before MFMAs.
template<int BM, int BN, int MODE>
__global__ __launch_bounds__(256) void gemm_split(
    const float* __restrict__ A, int lda,
    const float* __restrict__ W, int ldw,
    float* __restrict__ C, int ldc,
    int K, int NBX)
{
    constexpr int FM = BM / 32;
    constexpr int FN = BN / 32;
    constexpr int ACH = BM * 4;
    constexpr int TOT = (BM + BN) * 4;
    constexpr int CH = TOT / 256;        // chunks per thread
    __shared__ __attribute__((aligned(16))) _Float16 As[2][BM * 64];
    __shared__ __attribute__((aligned(16))) _Float16 Bs[2][BN * 64];

    int bid = blockIdx.x;
    int bx, by;
    if (MODE == 1) {
        int xcd = bid & 7, j = bid >> 3;
        bx = xcd * 32 + (j >> 4);
        by = j & 15;
        if (bx >= NBX) return;
    } else {
        int cpx = gridDim.x >> 3;
        int swz = (bid & 7) * cpx + (bid >> 3);
        bx = swz % NBX;
        by = swz / NBX;
    }
    int m0 = by * BM, n0 = bx * BN;

    int tid = threadIdx.x;
    int wid = tid >> 6, lane = tid & 63;
    int wm = wid >> 1, wn = wid & 1;
    int lr = lane & 15, lk = lane >> 4;

    floatx4 acc[FM][FN] = {};
    float4 p0[CH], p1[CH];

    auto LOAD = [&](int k0) {
#pragma unroll
        for (int c = 0; c < CH; ++c) {
            int i = tid + c * 256;
            bool isA = i < ACH;
            int jj = isA ? i : i - ACH;
            int r = jj >> 2, c8 = jj & 3;
            const float* src = isA ? (A + (size_t)(m0 + r) * lda + k0 + c8 * 8)
                                   : (W + (size_t)(n0 + r) * ldw + k0 + c8 * 8);
            p0[c] = *(const float4*)(src);
            p1[c] = *(const float4*)(src + 4);
        }
    };
    auto STORE = [&](int buf) {
#pragma unroll
        for (int c = 0; c < CH; ++c) {
            int i = tid + c * 256;
            bool isA = i < ACH;
            int jj = isA ? i : i - ACH;
            int r = jj >> 2, c8 = jj & 3;
            float vv[8] = {p0[c].x, p0[c].y, p0[c].z, p0[c].w,
                           p1[c].x, p1[c].y, p1[c].z, p1[c].w};
            half8 hi, lo;
#pragma unroll
            for (int e = 0; e < 8; ++e) {
                _Float16 h = (_Float16)vv[e];
                hi[e] = h;
                lo[e] = (_Float16)(vv[e] - (float)h);
            }
            _Float16* dst = (isA ? As[buf] : Bs[buf]) + r * 64;
            *(half8*)(dst + (((c8)     ^ (r & 7)) << 3)) = hi;
            *(half8*)(dst + (((c8 + 4) ^ (r & 7)) << 3)) = lo;
        }
    };

    LOAD(0);
    STORE(0);
    int cur = 0;
    for (int k0 = 0; k0 < K; k0 += 32) {
        __syncthreads();
        if (k0 + 32 < K) LOAD(k0 + 32);

        half8 ah[FM], al[FM], bh[FN], bl[FN];
#pragma unroll
        for (int f = 0; f < FM; ++f) {
            int r = wm * (BM / 2) + f * 16 + lr;
            const _Float16* p = As[cur] + r * 64;
            ah[f] = *(const half8*)(p + (((lk)     ^ (r & 7)) << 3));
            al[f] = *(const half8*)(p + (((lk + 4) ^ (r & 7)) << 3));
        }
#pragma unroll
        for (int f = 0; f < FN; ++f) {
            int r = wn * (BN / 2) + f * 16 + lr;
            const _Float16* p = Bs[cur] + r * 64;
            bh[f] = *(const half8*)(p + (((lk)     ^ (r & 7)) << 3));
            bl[f] = *(const half8*)(p + (((lk + 4) ^ (r & 7)) << 3));
        }
#pragma unroll
        for (int i2 = 0; i2 < FM; ++i2)
#pragma unroll
            for (int j2 = 0; j2 < FN; ++j2) {
                acc[i2][j2] = __builtin_amdgcn_mfma_f32_16x16x32_f16(ah[i2], bh[j2], acc[i2][j2], 0, 0, 0);
                acc[i2][j2] = __builtin_amdgcn_mfma_f32_16x16x32_f16(ah[i2], bl[j2], acc[i2][j2], 0, 0, 0);
                acc[i2][j2] = __builtin_amdgcn_mfma_f32_16x16x32_f16(al[i2], bh[j2], acc[i2][j2], 0, 0, 0);
            }
        if (k0 + 32 < K) STORE(cur ^ 1);
        cur ^= 1;
    }

#pragma unroll
    for (int f = 0; f < FM; ++f)
#pragma unroll
        for (int g = 0; g < FN; ++g) {
            int row = m0 + wm * (BM / 2) + f * 16 + (lane >> 4) * 4;
            int col = n0 + wn * (BN / 2) + g * 16 + (lane & 15);
#pragma unroll
            for (int j = 0; j < 4; ++j)
                C[(size_t)(row + j) * ldc + col] = acc[f][g][j];
        }
}

// ---------------------------------------------------------------------------
// fp32 VALU GEMM for x_proj (small N).
__global__ __launch_bounds__(256) void gemm_nt(
    const float* __restrict__ A, int lda,
    const float* __restrict__ W, int ldw,
    float* __restrict__ C, int ldc,
    int M, int N, int K)
{
    __shared__ float As[16][64];
    __shared__ float Bs[16][64];
    int tid = threadIdx.x;
    int tx = tid & 15, ty = tid >> 4;
    int m0 = blockIdx.y * 64, n0 = blockIdx.x * 64;
    int lr = tid >> 2;
    int lc = (tid & 3) * 4;
    float acc[4][4] = {};

    for (int k0 = 0; k0 < K; k0 += 16) {
        float4 a4 = *(const float4*)(A + (size_t)(m0 + lr) * lda + k0 + lc);
        float4 b4 = *(const float4*)(W + (size_t)(n0 + lr) * ldw + k0 + lc);
        As[lc + 0][lr] = a4.x; As[lc + 1][lr] = a4.y;
        As[lc + 2][lr] = a4.z; As[lc + 3][lr] = a4.w;
        Bs[lc + 0][lr] = b4.x; Bs[lc + 1][lr] = b4.y;
        Bs[lc + 2][lr] = b4.z; Bs[lc + 3][lr] = b4.w;
        __syncthreads();
#pragma unroll
        for (int k = 0; k < 16; ++k) {
            float4 av = *(const float4*)&As[k][ty * 4];
            float4 bv = *(const float4*)&Bs[k][tx * 4];
            float a_[4] = {av.x, av.y, av.z, av.w};
            float b_[4] = {bv.x, bv.y, bv.z, bv.w};
#pragma unroll
            for (int i = 0; i < 4; ++i)
#pragma unroll
                for (int j = 0; j < 4; ++j)
                    acc[i][j] += a_[i] * b_[j];
        }
        __syncthreads();
    }

#pragma unroll
    for (int i = 0; i < 4; ++i) {
        float4 o = {acc[i][0], acc[i][1], acc[i][2], acc[i][3]};
        *(float4*)(C + (size_t)(m0 + ty * 4 + i) * ldc + n0 + tx * 4) = o;
    }
}

// ---------------------------------------------------------------------------
__global__ __launch_bounds__(256) void conv_silu(const float* __restrict__ xz,
                                                 const float* __restrict__ cw,
                                                 const float* __restrict__ cb,
                                                 float* __restrict__ xi) {
    int idx = blockIdx.x * 256 + threadIdx.x;
    int d = idx & 1023;
    int t = (idx >> 10) & 1023;
    int b = idx >> 20;
    const float* base = xz + (size_t)(b * LL) * (2 * DINNER) + d;
    float acc = cb[d];
#pragma unroll
    for (int j = 0; j < DCONV; ++j) {
        int tt = t - 3 + j;
        if (tt >= 0) acc += cw[d * 4 + j] * base[(size_t)tt * (2 * DINNER)];
    }
    xi[idx] = acc / (1.f + expf(-acc));
}

// ---------------------------------------------------------------------------
// Selective scan, 16 chunks x 64 steps, dt_proj fused. LDS ~22.6 KB ->
// 7 blocks/CU. db (dbc[:,0:32] staging) overlaid with sC/sY.
template <int PASS>
__global__ __launch_bounds__(256) void scan_k(
    const float* __restrict__ xi, const float* __restrict__ dbc,
    const float* __restrict__ dtw, const float* __restrict__ dtb,
    const float* __restrict__ A_log, const float* __restrict__ Dskip,
    const float* __restrict__ xz,
    float* __restrict__ P, float* __restrict__ S,
    const float* __restrict__ H0, float* __restrict__ yg)
{
    __shared__ float sd[CHUNK][16], sx[CHUNK][16], sB[CHUNK][16];
    __shared__ float ovraw[CHUNK * 32];
    __shared__ float sdtT[32][16];
    __shared__ float sdtb[16];
    float (*db)[32] = (float(*)[32])ovraw;
    float (*sC)[16] = (float(*)[16])ovraw;
    float (*sY)[16] = (float(*)[16])(ovraw + CHUNK * 16);

    int c = blockIdx.x, dblk = blockIdx.y, b = blockIdx.z;
    int tid = threadIdx.x;
    int d0 = dblk * 16, t0 = c * CHUNK;

    for (int idx = tid; idx < 512; idx += 256)
        sdtT[idx >> 4][idx & 15] = dtw[(size_t)(d0 + (idx & 15)) * DTRANK + (idx >> 4)];
    if (tid < 16) sdtb[tid] = dtb[d0 + tid];
    for (int idx = tid; idx < CHUNK * 16; idx += 256) {
        int t = idx >> 4, i = idx & 15;
        size_t row = (size_t)(b * LL + t0 + t);
        sx[t][i] = xi[row * DINNER + d0 + i];
        sB[t][i] = dbc[row * 64 + DTRANK + i];
    }
    for (int idx = tid; idx < CHUNK * 8; idx += 256) {
        int t = idx >> 3, q = idx & 7;
        size_t row = (size_t)(b * LL + t0 + t);
        *(float4*)&db[t][q * 4] = *(const float4*)(dbc + row * 64 + q * 4);
    }
    __syncthreads();

    for (int idx = tid; idx < CHUNK * 16; idx += 256) {
        int t = idx >> 4, i = idx & 15;
        float a = sdtb[i];
#pragma unroll
        for (int k = 0; k < DTRANK; ++k) a += db[t][k] * sdtT[k][i];
        sd[t][i] = (a > 20.f) ? a : log1pf(expf(a));
    }
    __syncthreads();

    if (PASS == 3) {
        for (int idx = tid; idx < CHUNK * 16; idx += 256) {
            int t = idx >> 4, i = idx & 15;
            size_t row = (size_t)(b * LL + t0 + t);
            sC[t][i] = dbc[row * 64 + DTRANK + DSTATE + i];
        }
        __syncthreads();
    }

    int di = tid >> 4, n = tid & 15;
    int d = d0 + di;
    float Adn = -expf(A_log[d * DSTATE + n]);
    float Dsk = Dskip[d];
    float h = (PASS == 1) ? 0.f : H0[(size_t)(c * 2 + b) * 16384 + d * 16 + n];
    float ap = 1.f;

    for (int t = 0; t < CHUNK; ++t) {
        float dl = sd[t][di];
        float dA = expf(dl * Adn);
        h = dA * h + dl * sx[t][di] * sB[t][n];
        if (PASS == 1) {
            ap *= dA;
        } else {
            float p = h * sC[t][n];
            p += __shfl_xor(p, 1);
            p += __shfl_xor(p, 2);
            p += __shfl_xor(p, 4);
            p += __shfl_xor(p, 8);
            if (n == 0) sY[t][di] = p + sx[t][di] * Dsk;
        }
    }

    if (PASS == 1) {
        size_t o = (size_t)(c * 2 + b) * 16384 + d * 16 + n;
        P[o] = ap;
        S[o] = h;
    } else {
        __syncthreads();
        for (int idx = tid; idx < CHUNK * 16; idx += 256) {
            int t = idx >> 4, i = idx & 15;
            size_t row = (size_t)(b * LL + t0 + t);
            float z = xz[row * (2 * DINNER) + DINNER + d0 + i];
            yg[row * DINNER + d0 + i] = sY[t][i] * (z / (1.f + expf(-z)));
        }
    }
}

__global__ __launch_bounds__(256) void scan_carry(const float* __restrict__ P,
                                                  const float* __restrict__ S,
                                                  float* __restrict__ H0) {
    int idx = blockIdx.x * 256 + threadIdx.x;
    float carry = 0.f;
#pragma unroll
    for (int c = 0; c < NCH; ++c) {
        H0[(size_t)c * 32768 + idx] = carry;
        carry = P[(size_t)c * 32768 + idx] * carry + S[(size_t)c * 32768 + idx];
    }
}

// ---------------------------------------------------------------------------
__global__ __launch_bounds__(128) void lnorm(const float* __restrict__ x,
                                             const float* __restrict__ w,
                                             const float* __restrict__ bp,
                                             float* __restrict__ xn) {
    int row = blockIdx.x;
    int tid = threadIdx.x;
    float4 v = *(const float4*)(x + (size_t)row * DMODEL + tid * 4);
    float s = v.x + v.y + v.z + v.w;
    float q = v.x * v.x + v.y * v.y + v.z * v.z + v.w * v.w;
#pragma unroll
    for (int m = 1; m < 64; m <<= 1) {
        s += __shfl_xor(s, m);
        q += __shfl_xor(q, m);
    }
    __shared__ float ss[2], qq[2];
    if ((tid & 63) == 0) { ss[tid >> 6] = s; qq[tid >> 6] = q; }
    __syncthreads();
    s = ss[0] + ss[1];
    q = qq[0] + qq[1];
    float mu = s / (float)DMODEL;
    float var = q / (float)DMODEL - mu * mu;
    float r = rsqrtf(var + 1e-5f);
    int c = tid * 4;
    float4 o;
    o.x = (v.x - mu) * r * w[c + 0] + bp[c + 0];
    o.y = (v.y - mu) * r * w[c + 1] + bp[c + 1];
    o.z = (v.z - mu) * r * w[c + 2] + bp[c + 2];
    o.w = (v.w - mu) * r * w[c + 3] + bp[c + 3];
    *(float4*)(xn + (size_t)row * DMODEL + c) = o;
}

// ---------------------------------------------------------------------------
// Pre-split fp32 [N][512] -> f16 hi/lo in MFMA-fragment-tiled layout:
// flat = (kc*NT + nt)*512 + lane*8 + e ; n = nt*16+(lane&15), k = kc*32+(lane>>4)*8+e
__global__ __launch_bounds__(256) void split16(const float* __restrict__ src,
                                               _Float16* __restrict__ hi,
                                               _Float16* __restrict__ lo,
                                               int NT) {
    int g = blockIdx.x * 256 + threadIdx.x;
    int lane = g & 63;
    int tl = g >> 6;
    int nt = tl % NT, kc = tl / NT;
    int n = nt * 16 + (lane & 15);
    int k = kc * 32 + (lane >> 4) * 8;
    const float* s = src + (size_t)n * 512 + k;
    float4 v0 = *(const float4*)(s);
    float4 v1 = *(const float4*)(s + 4);
    float vv[8] = {v0.x, v0.y, v0.z, v0.w, v1.x, v1.y, v1.z, v1.w};
    half8 h, l;
#pragma unroll
    for (int e = 0; e < 8; ++e) {
        _Float16 hh = (_Float16)vv[e];
        h[e] = hh;
        l[e] = (_Float16)(vv[e] - (float)hh);
    }
    *(half8*)(hi + (size_t)g * 8) = h;
    *(half8*)(lo + (size_t)g * 8) = l;
}

// ---------------------------------------------------------------------------
// Head GEMM from pre-split tiled f16: global_load_lds staging (zero VALU),
// linear conflict-free LDS, double-buffered, col-slice-per-XCD mapping.
__global__ __launch_bounds__(256) void gemm_head(
    const _Float16* __restrict__ Ah, const _Float16* __restrict__ Al,
    const _Float16* __restrict__ Wh, const _Float16* __restrict__ Wl,
    float* __restrict__ C)
{
    __shared__ __attribute__((aligned(16))) _Float16 lds[2][4][8][512];  // 64 KB
    int bid = blockIdx.x;
    int xcd = bid & 7, j = bid >> 3;
    int bx = xcd * 32 + (j >> 4);
    int by = j & 15;
    if (bx >= 250) return;

    int tid = threadIdx.x;
    int wid = tid >> 6, lane = tid & 63;
    int wm = wid >> 1, wn = wid & 1;
    floatx4 acc[4][4] = {};

    auto STAGE = [&](int buf, int kc) {
        int t0 = wid * 2;
#pragma unroll
        for (int t = t0; t < t0 + 2; ++t) {
            size_t ao = ((size_t)kc * 128 + by * 8 + t) * 512 + lane * 8;
            size_t bo = ((size_t)kc * 2000 + bx * 8 + t) * 512 + lane * 8;
            gload16(Ah + ao, &lds[buf][0][t][0]);
            gload16(Al + ao, &lds[buf][1][t][0]);
            gload16(Wh + bo, &lds[buf][2][t][0]);
            gload16(Wl + bo, &lds[buf][3][t][0]);
        }
    };

    STAGE(0, 0);
    __syncthreads();
    int cur = 0;
    for (int kc = 0; kc < 16; ++kc) {
        if (kc < 15) STAGE(cur ^ 1, kc + 1);
        half8 ah[4], al[4], bh[4], bl[4];
#pragma unroll
        for (int f = 0; f < 4; ++f) {
            ah[f] = *(const half8*)&lds[cur][0][wm * 4 + f][lane * 8];
            al[f] = *(const half8*)&lds[cur][1][wm * 4 + f][lane * 8];
            bh[f] = *(const half8*)&lds[cur][2][wn * 4 + f][lane * 8];
            bl[f] = *(const half8*)&lds[cur][3][wn * 4 + f][lane * 8];
        }
#pragma unroll
        for (int f = 0; f < 4; ++f)
#pragma unroll
            for (int g = 0; g < 4; ++g) {
                acc[f][g] = __builtin_amdgcn_mfma_f32_16x16x32_f16(ah[f], bh[g], acc[f][g], 0, 0, 0);
                acc[f][g] = __builtin_amdgcn_mfma_f32_16x16x32_f16(ah[f], bl[g], acc[f][g], 0, 0, 0);
                acc[f][g] = __builtin_amdgcn_mfma_f32_16x16x32_f16(al[f], bh[g], acc[f][g], 0, 0, 0);
            }
        __syncthreads();
        cur ^= 1;
    }

#pragma unroll
    for (int f = 0; f < 4; ++f)
#pragma unroll
        for (int g = 0; g < 4; ++g) {
            int row = by * 128 + wm * 64 + f * 16 + (lane >> 4) * 4;
            int col = bx * 128 + wn * 64 + g * 16 + (lane & 15);
#pragma unroll
            for (int jj = 0; jj < 4; ++jj)
                C[(size_t)(row + jj) * VOCAB + col] = acc[f][g][jj];
        }
}

// ---------------------------------------------------------------------------
extern "C" void kernel_launch(void* const* d_in, const int* in_sizes, int n_in,
                              void* d_out, int out_size, void* d_ws, size_t ws_size,
                              hipStream_t stream) {
    const int*   tokens = (const int*)d_in[0];
    const float* embed  = (const float*)d_in[1];
    const float* inw    = (const float*)d_in[2];
    const float* cw     = (const float*)d_in[3];
    const float* cb     = (const float*)d_in[4];
    const float* xpw    = (const float*)d_in[5];
    const float* dtw    = (const float*)d_in[6];
    const float* dtb    = (const float*)d_in[7];
    const float* Alog   = (const float*)d_in[8];
    const float* Dsk    = (const float*)d_in[9];
    const float* outw   = (const float*)d_in[10];
    const float* nw     = (const float*)d_in[11];
    const float* nb     = (const float*)d_in[12];
    const float* hw     = (const float*)d_in[13];
    float* out = (float*)d_out;

    float* ws = (float*)d_ws;
    // Persistent layout (floats): xn first so head overlay can reuse the rest.
    float* xn  = ws;                            // 1M
    float* x   = ws + (1u << 20);               // 1M
    float* xz  = ws + (2u << 20);               // 4M
    float* xib = ws + (6u << 20);               // 2M
    float* dbc = ws + (8u << 20);               // 128K
    float* yg  = dbc + (1 << 17);               // 2M
    float* Pb  = yg + (2u << 20);               // 512K
    float* Sb  = Pb + (1 << 19);                // 512K
    float* H0  = Sb + (1 << 19);                // 512K

    // Head overlay (over x, xz, ... — dead after lnorm): starts at byte 4 MB.
    _Float16* Hbase = (_Float16*)(ws + (1u << 20));
    _Float16* Wh = Hbase;                       // 16,384,000 halves
    _Float16* Wl = Wh + (size_t)VOCAB * 512;
    _Float16* Ahh = Wl + (size_t)VOCAB * 512;   // 1,048,576 halves
    _Float16* All = Ahh + (size_t)ROWS * 512;
    bool fast_head = ws_size >= (size_t)74 * 1024 * 1024;

    embed_k<<<ROWS, 128, 0, stream>>>(tokens, embed, x);

    for (int l = 0; l < NLAYERS; ++l) {
        const float* inw_l  = inw  + (size_t)l * 2 * DINNER * DMODEL;
        const float* cw_l   = cw   + (size_t)l * DINNER * DCONV;
        const float* cb_l   = cb   + (size_t)l * DINNER;
        const float* xpw_l  = xpw  + (size_t)l * 64 * DINNER;
        const float* dtw_l  = dtw  + (size_t)l * DINNER * DTRANK;
        const float* dtb_l  = dtb  + (size_t)l * DINNER;
        const float* Alog_l = Alog + (size_t)l * DINNER * DSTATE;
        const float* Dsk_l  = Dsk  + (size_t)l * DINNER;
        const float* outw_l = outw + (size_t)l * DMODEL * DINNER;

        gemm_split<128, 128, 0><<<16 * 16, 256, 0, stream>>>(
            x, DMODEL, inw_l, DMODEL, xz, 2 * DINNER, DMODEL, 16);
        conv_silu<<<(ROWS * DINNER) / 256, 256, 0, stream>>>(xz, cw_l, cb_l, xib);
        gemm_nt<<<dim3(1, ROWS / 64), 256, 0, stream>>>(
            xib, DINNER, xpw_l, DINNER, dbc, 64, ROWS, 64, DINNER);
        scan_k<1><<<dim3(NCH, DINNER / 16, BB), 256, 0, stream>>>(
            xib, dbc, dtw_l, dtb_l, Alog_l, Dsk_l, xz, Pb, Sb, nullptr, nullptr);
        scan_carry<<<128, 256, 0, stream>>>(Pb, Sb, H0);
        scan_k<3><<<dim3(NCH, DINNER / 16, BB), 256, 0, stream>>>(
            xib, dbc, dtw_l, dtb_l, Alog_l, Dsk_l, xz, nullptr, nullptr, H0, yg);
        gemm_split<64, 64, 0><<<32 * 8, 256, 0, stream>>>(
            yg, DINNER, outw_l, DINNER, x, DMODEL, DINNER, 8);
    }

    lnorm<<<ROWS, 128, 0, stream>>>(x, nw, nb, xn);

    if (fast_head) {
        split16<<<8000, 256, 0, stream>>>(hw, Wh, Wl, VOCAB / 16);
        split16<<<512, 256, 0, stream>>>(xn, Ahh, All, ROWS / 16);
        gemm_head<<<4096, 256, 0, stream>>>(Ahh, All, Wh, Wl, out);
    } else {
        gemm_split<128, 128, 1><<<4096, 256, 0, stream>>>(
            xn, DMODEL, hw, DMODEL, out, VOCAB, DMODEL, 250);
    }
}